// Round 9
// baseline (173.463 us; speedup 1.0000x reference)
//
#include <hip/hip_runtime.h>
#include <hip/hip_bf16.h>

#define BB   256
#define SS   2048
#define DIN  32
#define DSL  64
#define KSEL 8

// ws layout: [0, BB*SS) f32 scores  |  then BB*SS*DSL bf16 h1 (TILED)
// h1 tiled layout (elements): elem(r, j) at (r>>6)*4096 + (j>>3)*512 + (r&63)*8 + (j&7)
//   -> k1 writes 16B/lane, lane-contiguous (1KB full-line wave stores)
//   -> k2 reads 16B/lane, 8 lanes cover 128B contiguous per jb-block
// d_out layout: sel [B,K,64] | ctx [B,64] | attnW [B,S]  (f32, concat flat)

static __device__ __forceinline__ float bflo(unsigned int u) {
    return __uint_as_float(u << 16);
}
static __device__ __forceinline__ float bfhi(unsigned int u) {
    return __uint_as_float(u & 0xFFFF0000u);
}
static __device__ __forceinline__ unsigned int bf16bits(float f) {
    __hip_bfloat16 h = __float2bfloat16(f);  // RNE
    unsigned short u;
    __builtin_memcpy(&u, &h, 2);
    return (unsigned int)u;
}

// ---------------- Kernel 1: h1 (bf16, tiled) + scores (f32) ----------------
// 512 blocks x 256. Each wave handles 256 slots (4 per lane): 4 independent
// FMA chains saturate VALU issue; W-row LDS broadcasts amortized over 128 FMAs.
__global__ __launch_bounds__(256, 2)
void k1_mlp_scores(const float* __restrict__ feats,
                   const float* __restrict__ W1, const float* __restrict__ b1,
                   const float* __restrict__ W2, const float* __restrict__ b2,
                   const float* __restrict__ q,
                   float* __restrict__ scores_ws,
                   unsigned short* __restrict__ h1_ws) {
    // Wl row j (stride 36 floats = 144B, 16B-aligned): [w0..w31, b1j, vj, pad, pad]
    __shared__ float Wl[DSL * 36 + 1];
    const int t = threadIdx.x;

    if (t < DSL) {
        const int j = t;
#pragma unroll
        for (int i = 0; i < DIN; ++i) Wl[j * 36 + i] = W1[i * DSL + j];
        float vj = 0.f;
        for (int d = 0; d < DSL; ++d)
            vj = fmaf(W2[j * DSL + d], q[d] + q[DSL + d], vj);
        Wl[j * 36 + 32] = b1[j];
        Wl[j * 36 + 33] = vj * 0.0625f;  // 0.5 (head mean) * 0.125 (1/sqrt(64))
    } else if (t == DSL) {
        float c0 = 0.f;
        for (int d = 0; d < DSL; ++d)
            c0 = fmaf(b2[d], q[d] + q[DSL + d], c0);
        Wl[DSL * 36] = c0 * 0.0625f;
    }
    __syncthreads();

    const int lane = t & 63;
    const int wave = t >> 6;
    const long base = (long)blockIdx.x * 1024 + (long)wave * 256;
    const long tile0 = base >> 6;  // 4 consecutive 64-row tiles per wave

    // load 4 x-rows into VGPRs (32 independent 16B loads in flight)
    float x[4][DIN];
#pragma unroll
    for (int ss = 0; ss < 4; ++ss) {
        const float4* p = (const float4*)(feats + (base + ss * 64 + lane) * DIN);
#pragma unroll
        for (int i4 = 0; i4 < DIN / 4; ++i4) {
            float4 v = p[i4];
            x[ss][4 * i4 + 0] = v.x; x[ss][4 * i4 + 1] = v.y;
            x[ss][4 * i4 + 2] = v.z; x[ss][4 * i4 + 3] = v.w;
        }
    }

    const float c0 = Wl[DSL * 36];
    float sc[4] = {c0, c0, c0, c0};
    unsigned short* hp0 = h1_ws + (tile0 << 12) + (lane << 3);

    for (int jb = 0; jb < 8; ++jb) {
        unsigned int pk[4][4];
#pragma unroll
        for (int jo = 0; jo < 8; ++jo) {
            const int j = jb * 8 + jo;
            const float4* wr4 = (const float4*)&Wl[j * 36];
            const float2 bv = *(const float2*)&Wl[j * 36 + 32];  // (b1j, vj)
            float h[4] = {bv.x, bv.x, bv.x, bv.x};
#pragma unroll
            for (int i4 = 0; i4 < DIN / 4; ++i4) {
                float4 w = wr4[i4];
#pragma unroll
                for (int ss = 0; ss < 4; ++ss) {
                    h[ss] = fmaf(x[ss][4 * i4 + 0], w.x, h[ss]);
                    h[ss] = fmaf(x[ss][4 * i4 + 1], w.y, h[ss]);
                    h[ss] = fmaf(x[ss][4 * i4 + 2], w.z, h[ss]);
                    h[ss] = fmaf(x[ss][4 * i4 + 3], w.w, h[ss]);
                }
            }
#pragma unroll
            for (int ss = 0; ss < 4; ++ss) {
                h[ss] = fmaxf(h[ss], 0.f);
                sc[ss] = fmaf(h[ss], bv.y, sc[ss]);
                if ((jo & 1) == 0) pk[ss][jo >> 1] = bf16bits(h[ss]);
                else               pk[ss][jo >> 1] |= bf16bits(h[ss]) << 16;
            }
        }
        // coalesced: 64 lanes x 16B = 1KB contiguous per wave store, x4 tiles
#pragma unroll
        for (int ss = 0; ss < 4; ++ss)
            *(uint4*)(hp0 + ((long)ss << 12) + (jb << 9)) =
                make_uint4(pk[ss][0], pk[ss][1], pk[ss][2], pk[ss][3]);
    }
#pragma unroll
    for (int ss = 0; ss < 4; ++ss)
        scores_ws[base + ss * 64 + lane] = sc[ss];  // coalesced
}

// ---------------- Kernel 2: softmax + ctx + topk + sel (1024 thr) ----------
#define T2 1024
#define W2C (T2 / 64)  // 16 waves

__global__ __launch_bounds__(T2)
void k2_attend(const float* __restrict__ feats,
               const void* __restrict__ maskp,
               const float* __restrict__ W1, const float* __restrict__ b1,
               const float* __restrict__ W2, const float* __restrict__ b2,
               const float* __restrict__ scores_ws,
               const unsigned short* __restrict__ h1_ws,
               float* __restrict__ sel_out,
               float* __restrict__ ctx_out,
               float* __restrict__ attn_out) {
    __shared__ float scm[SS];          // masked scores (-inf at masked)
    __shared__ float wbuf[SS];         // exp / attnW
    __shared__ float red[W2C * DSL];   // cross-wave reduction scratch
    __shared__ float ubar[DSL];
    __shared__ float wredf[W2C];
    __shared__ float wargv[W2C];
    __shared__ int   wargi[W2C];
    __shared__ int   topidx[KSEL];
    __shared__ int   maskIsByte;
    __shared__ float xsel[KSEL][DIN];
    __shared__ float h1sel[KSEL][DSL];

    const int t = threadIdx.x;
    const int b = blockIdx.x;
    const int lane = t & 63;
    const int wv = t >> 6;

    // --- mask dtype detection: int32 {0,1} has zero bytes at %4!=0 ---
    if (t == 0) maskIsByte = 0;
    __syncthreads();
    {
        unsigned int u = ((const unsigned int*)maskp)[t];  // first 4KB (mask >= 512KB)
        if ((u & 0xFFFFFF00u) != 0u) atomicOr(&maskIsByte, 1);
    }
    __syncthreads();
    const bool mbyte = (maskIsByte != 0);

    // --- Phase A: load + mask scores ---
    for (int s = t; s < SS; s += T2) {
        float v = scores_ws[(size_t)b * SS + s];
        bool mk = mbyte ? (((const unsigned char*)maskp)[(size_t)b * SS + s] != 0)
                        : (((const int*)maskp)[(size_t)b * SS + s] != 0);
        scm[s] = mk ? v : -INFINITY;
    }
    __syncthreads();

    // --- Phase B: masked softmax -> attnW ---
    float lm = -INFINITY;
    for (int s = t; s < SS; s += T2) lm = fmaxf(lm, scm[s]);
#pragma unroll
    for (int o = 1; o < 64; o <<= 1) lm = fmaxf(lm, __shfl_xor(lm, o));
    if (lane == 0) wredf[wv] = lm;
    __syncthreads();
    float m = wredf[0];
#pragma unroll
    for (int i = 1; i < W2C; ++i) m = fmaxf(m, wredf[i]);
    __syncthreads();  // protect wredf before re-use

    float lz = 0.f;
    if (m == -INFINITY) {  // all-masked row: reference -> uniform softmax
        for (int s = t; s < SS; s += T2) wbuf[s] = 1.f;
        lz = (float)(SS / T2);
    } else {
        for (int s = t; s < SS; s += T2) {
            float e = __expf(scm[s] - m);  // exp(-inf)=0 for masked
            wbuf[s] = e;
            lz += e;
        }
    }
#pragma unroll
    for (int o = 1; o < 64; o <<= 1) lz += __shfl_xor(lz, o);
    if (lane == 0) wredf[wv] = lz;
    __syncthreads();
    float Z = wredf[0];
#pragma unroll
    for (int i = 1; i < W2C; ++i) Z += wredf[i];
    const float invZ = 1.f / Z;
    for (int s = t; s < SS; s += T2) {
        float w = wbuf[s] * invZ;
        wbuf[s] = w;
        attn_out[(size_t)b * SS + s] = w;
    }
    __syncthreads();

    // --- Phase C: u[j] = sum_s attnW[s]*h1[s][j]  (tiled bf16 h1) ---
    const int jb = t & 7;        // j-block: j = jb*8 + m
    const int sg = t >> 3;       // 0..127
    float u8[8] = {0.f, 0.f, 0.f, 0.f, 0.f, 0.f, 0.f, 0.f};
    const unsigned short* hb =
        h1_ws + (size_t)b * (SS * DSL)
              + ((size_t)(sg >> 6) << 12) + (jb << 9) + ((sg & 63) << 3);
    for (int k = 0; k < SS / 128; ++k) {  // 16 iters
        float w = wbuf[sg + (k << 7)];
        uint4 hv = *(const uint4*)(hb + ((size_t)k << 13));
        u8[0] = fmaf(w, bflo(hv.x), u8[0]);
        u8[1] = fmaf(w, bfhi(hv.x), u8[1]);
        u8[2] = fmaf(w, bflo(hv.y), u8[2]);
        u8[3] = fmaf(w, bfhi(hv.y), u8[3]);
        u8[4] = fmaf(w, bflo(hv.z), u8[4]);
        u8[5] = fmaf(w, bfhi(hv.z), u8[5]);
        u8[6] = fmaf(w, bflo(hv.w), u8[6]);
        u8[7] = fmaf(w, bfhi(hv.w), u8[7]);
    }
    // sum the 8 sg-subgroups within each wave (lane bits 3..5)
#pragma unroll
    for (int o = 8; o <= 32; o <<= 1) {
#pragma unroll
        for (int mm = 0; mm < 8; ++mm) u8[mm] += __shfl_xor(u8[mm], o);
    }
    if (lane < 8) {
#pragma unroll
        for (int mm = 0; mm < 8; ++mm) red[wv * DSL + lane * 8 + mm] = u8[mm];
    }
    __syncthreads();
    if (t < DSL) {
        float acc = 0.f;
#pragma unroll
        for (int w2i = 0; w2i < W2C; ++w2i) acc += red[w2i * DSL + t];
        ubar[t] = acc;
    }
    __syncthreads();

    // --- Phase D: ctx = u @ W2 + b2 (16 waves, 4 j's each) ---
    {
        float acc = (wv == 0) ? b2[lane] : 0.f;
        for (int jj = wv * 4; jj < wv * 4 + 4; ++jj)
            acc = fmaf(ubar[jj], W2[jj * DSL + lane], acc);
        red[wv * DSL + lane] = acc;
    }
    __syncthreads();
    if (t < DSL) {
        float acc = 0.f;
#pragma unroll
        for (int w2i = 0; w2i < W2C; ++w2i) acc += red[w2i * DSL + t];
        ctx_out[(size_t)b * DSL + t] = acc;
    }

    // --- Phase E: top-K (descending value, ties -> lower index) ---
    for (int k = 0; k < KSEL; ++k) {
        // seed with s=t so an all -inf row still yields valid indices
        float bvv = scm[t];
        int bi = t;
#pragma unroll
        for (int kk = 1; kk < SS / T2; ++kk) {  // ascending index
            int s = t + kk * T2;
            float v = scm[s];
            if (v > bvv) { bvv = v; bi = s; }
        }
#pragma unroll
        for (int o = 1; o < 64; o <<= 1) {
            float ov = __shfl_xor(bvv, o);
            int oi = __shfl_xor(bi, o);
            if (ov > bvv || (ov == bvv && oi < bi)) { bvv = ov; bi = oi; }
        }
        if (lane == 0) { wargv[wv] = bvv; wargi[wv] = bi; }
        __syncthreads();
        if (t == 0) {
            float Bv = wargv[0]; int Bi = wargi[0];
            for (int w2i = 1; w2i < W2C; ++w2i) {
                float ov = wargv[w2i]; int oi = wargi[w2i];
                if (ov > Bv || (ov == Bv && oi < Bi)) { Bv = ov; Bi = oi; }
            }
            topidx[k] = Bi;
            scm[Bi] = -INFINITY;
        }
        __syncthreads();
    }

    // --- Phase F: sel = full f32 MLP recompute of the K selected rows ---
    if (t < KSEL * DIN) {
        int k = t >> 5, i = t & 31;
        xsel[k][i] = feats[((size_t)b * SS + topidx[k]) * DIN + i];
    }
    __syncthreads();
    if (wv < KSEL) {
        const int k = wv;
        float h = b1[lane];
#pragma unroll
        for (int i = 0; i < DIN; ++i) h = fmaf(xsel[k][i], W1[i * DSL + lane], h);
        h1sel[k][lane] = fmaxf(h, 0.f);
    }
    __syncthreads();
    if (wv < KSEL) {
        const int k = wv;
        float acc = b2[lane];
        for (int jj = 0; jj < DSL; ++jj)
            acc = fmaf(h1sel[k][jj], W2[jj * DSL + lane], acc);
        sel_out[((size_t)b * KSEL + k) * DSL + lane] = acc;
    }
}

extern "C" void kernel_launch(void* const* d_in, const int* in_sizes, int n_in,
                              void* d_out, int out_size, void* d_ws, size_t ws_size,
                              hipStream_t stream) {
    const float* feats = (const float*)d_in[0];
    const void*  mask  = d_in[1];
    const float* W1 = (const float*)d_in[2];
    const float* b1 = (const float*)d_in[3];
    const float* W2 = (const float*)d_in[4];
    const float* b2 = (const float*)d_in[5];
    const float* q  = (const float*)d_in[6];

    float* scores_ws = (float*)d_ws;
    unsigned short* h1_ws =
        (unsigned short*)((char*)d_ws + (size_t)BB * SS * sizeof(float));

    float* sel_out  = (float*)d_out;                       // B*K*64
    float* ctx_out  = sel_out + (size_t)BB * KSEL * DSL;   // B*64
    float* attn_out = ctx_out + (size_t)BB * DSL;          // B*S

    hipLaunchKernelGGL(k1_mlp_scores, dim3(BB * SS / 1024), dim3(256), 0, stream,
                       feats, W1, b1, W2, b2, q, scores_ws, h1_ws);
    hipLaunchKernelGGL(k2_attend, dim3(BB), dim3(T2), 0, stream,
                       feats, mask, W1, b1, W2, b2, scores_ws, h1_ws,
                       sel_out, ctx_out, attn_out);
}

// Round 10
// 166.902 us; speedup vs baseline: 1.0393x; 1.0393x over previous
//
#include <hip/hip_runtime.h>
#include <hip/hip_bf16.h>

#define BB   256
#define SS   2048
#define DIN  32
#define DSL  64
#define KSEL 8

// ws layout: [0, BB*SS) f32 scores  |  then BB*SS*DSL bf16 h1 (TILED)
// h1 tiled layout (elements): elem(r, j) at (r>>6)*4096 + (j>>3)*512 + (r&63)*8 + (j&7)
//   -> k1 writes 16B/lane, lane-contiguous (1KB full-line wave stores)
//   -> k2 reads 16B/lane, 8 lanes cover 128B contiguous per jb-block
// d_out layout: sel [B,K,64] | ctx [B,64] | attnW [B,S]  (f32, concat flat)

static __device__ __forceinline__ float bflo(unsigned int u) {
    return __uint_as_float(u << 16);
}
static __device__ __forceinline__ float bfhi(unsigned int u) {
    return __uint_as_float(u & 0xFFFF0000u);
}
static __device__ __forceinline__ unsigned int bf16bits(float f) {
    __hip_bfloat16 h = __float2bfloat16(f);  // RNE
    unsigned short u;
    __builtin_memcpy(&u, &h, 2);
    return (unsigned int)u;
}

// ---------------- Kernel 1: h1 (bf16, tiled) + scores (f32) ----------------
// 2048 blocks x 256. One slot per lane; ALL 64 output channels accumulate in
// VGPRs (h[64]); the weight row W1[i][:] is wave-uniform -> scalar s_load on
// the scalar pipe (no LDS in the main loop); 64 independent v_fmac per i-step.
__global__ __launch_bounds__(256)
void k1_mlp_scores(const float* __restrict__ feats,
                   const float* __restrict__ W1, const float* __restrict__ b1,
                   const float* __restrict__ W2, const float* __restrict__ b2,
                   const float* __restrict__ q,
                   float* __restrict__ scores_ws,
                   unsigned short* __restrict__ h1_ws) {
    __shared__ float2 vb[DSL];   // (b1j, vj)
    __shared__ float c0s;
    const int t = threadIdx.x;

    // prologue: v = W2 @ qbar / 16 (one read of W2 per block), b1 staged
    if (t < DSL) {
        const int j = t;
        float vj = 0.f;
        for (int d = 0; d < DSL; ++d)
            vj = fmaf(W2[j * DSL + d], q[d] + q[DSL + d], vj);
        vb[j] = make_float2(b1[j], vj * 0.0625f);  // 0.5 head-mean * 0.125 scale
    } else if (t == DSL) {
        float c0 = 0.f;
        for (int d = 0; d < DSL; ++d)
            c0 = fmaf(b2[d], q[d] + q[DSL + d], c0);
        c0s = c0 * 0.0625f;
    }
    __syncthreads();

    const int lane = t & 63;
    const int wave = t >> 6;
    const long slot = (long)blockIdx.x * 256 + wave * 64 + lane;
    const long tile = slot >> 6;  // wave-uniform

    // x row in VGPRs
    float x[DIN];
    {
        const float4* p = (const float4*)(feats + slot * DIN);
#pragma unroll
        for (int i4 = 0; i4 < DIN / 4; ++i4) {
            float4 v = p[i4];
            x[4 * i4 + 0] = v.x; x[4 * i4 + 1] = v.y;
            x[4 * i4 + 2] = v.z; x[4 * i4 + 3] = v.w;
        }
    }

    // h[j] accumulators, fully unrolled (static indexing -> registers)
    float h[DSL];
#pragma unroll
    for (int j = 0; j < DSL; ++j) h[j] = 0.f;

#pragma unroll
    for (int i = 0; i < DIN; ++i) {
        const float* wr = W1 + i * DSL;  // wave-uniform address -> s_load
#pragma unroll
        for (int j = 0; j < DSL; ++j)
            h[j] = fmaf(x[i], wr[j], h[j]);  // v_fmac v,s,v
    }

    // epilogue: bias, relu, score dot, bf16 pack, tiled store
    float sc = c0s;
    unsigned short* hp = h1_ws + (tile << 12) + (lane << 3);
#pragma unroll
    for (int jb = 0; jb < 8; ++jb) {
        unsigned int pk[4];
#pragma unroll
        for (int jo = 0; jo < 8; ++jo) {
            const int j = jb * 8 + jo;
            float2 bv = vb[j];  // wave-uniform LDS read (epilogue only)
            float hv = fmaxf(h[j] + bv.x, 0.f);
            sc = fmaf(hv, bv.y, sc);
            if ((jo & 1) == 0) pk[jo >> 1] = bf16bits(hv);
            else               pk[jo >> 1] |= bf16bits(hv) << 16;
        }
        // 64 lanes x 16B = 1KB contiguous per wave store
        *(uint4*)(hp + (jb << 9)) = make_uint4(pk[0], pk[1], pk[2], pk[3]);
    }
    scores_ws[slot] = sc;  // coalesced
}

// ---------------- Kernel 2: softmax + ctx + topk + sel (1024 thr) ----------
#define T2 1024
#define W2C (T2 / 64)  // 16 waves

__global__ __launch_bounds__(T2)
void k2_attend(const float* __restrict__ feats,
               const void* __restrict__ maskp,
               const float* __restrict__ W1, const float* __restrict__ b1,
               const float* __restrict__ W2, const float* __restrict__ b2,
               const float* __restrict__ scores_ws,
               const unsigned short* __restrict__ h1_ws,
               float* __restrict__ sel_out,
               float* __restrict__ ctx_out,
               float* __restrict__ attn_out) {
    __shared__ float scm[SS];          // masked scores (-inf at masked)
    __shared__ float wbuf[SS];         // exp / attnW
    __shared__ float red[W2C * DSL];   // cross-wave reduction scratch
    __shared__ float ubar[DSL];
    __shared__ float wredf[W2C];
    __shared__ float wargv[W2C];
    __shared__ int   wargi[W2C];
    __shared__ int   topidx[KSEL];
    __shared__ int   maskIsByte;
    __shared__ float xsel[KSEL][DIN];
    __shared__ float h1sel[KSEL][DSL];

    const int t = threadIdx.x;
    const int b = blockIdx.x;
    const int lane = t & 63;
    const int wv = t >> 6;

    // --- mask dtype detection: int32 {0,1} has zero bytes at %4!=0 ---
    if (t == 0) maskIsByte = 0;
    __syncthreads();
    {
        unsigned int u = ((const unsigned int*)maskp)[t];  // first 4KB (mask >= 512KB)
        if ((u & 0xFFFFFF00u) != 0u) atomicOr(&maskIsByte, 1);
    }
    __syncthreads();
    const bool mbyte = (maskIsByte != 0);

    // --- Phase A: load + mask scores ---
    for (int s = t; s < SS; s += T2) {
        float v = scores_ws[(size_t)b * SS + s];
        bool mk = mbyte ? (((const unsigned char*)maskp)[(size_t)b * SS + s] != 0)
                        : (((const int*)maskp)[(size_t)b * SS + s] != 0);
        scm[s] = mk ? v : -INFINITY;
    }
    __syncthreads();

    // --- Phase B: masked softmax -> attnW ---
    float lm = -INFINITY;
    for (int s = t; s < SS; s += T2) lm = fmaxf(lm, scm[s]);
#pragma unroll
    for (int o = 1; o < 64; o <<= 1) lm = fmaxf(lm, __shfl_xor(lm, o));
    if (lane == 0) wredf[wv] = lm;
    __syncthreads();
    float m = wredf[0];
#pragma unroll
    for (int i = 1; i < W2C; ++i) m = fmaxf(m, wredf[i]);
    __syncthreads();  // protect wredf before re-use

    float lz = 0.f;
    if (m == -INFINITY) {  // all-masked row: reference -> uniform softmax
        for (int s = t; s < SS; s += T2) wbuf[s] = 1.f;
        lz = (float)(SS / T2);
    } else {
        for (int s = t; s < SS; s += T2) {
            float e = __expf(scm[s] - m);  // exp(-inf)=0 for masked
            wbuf[s] = e;
            lz += e;
        }
    }
#pragma unroll
    for (int o = 1; o < 64; o <<= 1) lz += __shfl_xor(lz, o);
    if (lane == 0) wredf[wv] = lz;
    __syncthreads();
    float Z = wredf[0];
#pragma unroll
    for (int i = 1; i < W2C; ++i) Z += wredf[i];
    const float invZ = 1.f / Z;
    for (int s = t; s < SS; s += T2) {
        float w = wbuf[s] * invZ;
        wbuf[s] = w;
        attn_out[(size_t)b * SS + s] = w;
    }
    __syncthreads();

    // --- Phase C: u[j] = sum_s attnW[s]*h1[s][j]  (tiled bf16 h1) ---
    const int jb = t & 7;        // j-block: j = jb*8 + m
    const int sg = t >> 3;       // 0..127
    float u8[8] = {0.f, 0.f, 0.f, 0.f, 0.f, 0.f, 0.f, 0.f};
    const unsigned short* hb =
        h1_ws + (size_t)b * (SS * DSL)
              + ((size_t)(sg >> 6) << 12) + (jb << 9) + ((sg & 63) << 3);
    for (int k = 0; k < SS / 128; ++k) {  // 16 iters
        float w = wbuf[sg + (k << 7)];
        uint4 hv = *(const uint4*)(hb + ((size_t)k << 13));
        u8[0] = fmaf(w, bflo(hv.x), u8[0]);
        u8[1] = fmaf(w, bfhi(hv.x), u8[1]);
        u8[2] = fmaf(w, bflo(hv.y), u8[2]);
        u8[3] = fmaf(w, bfhi(hv.y), u8[3]);
        u8[4] = fmaf(w, bflo(hv.z), u8[4]);
        u8[5] = fmaf(w, bfhi(hv.z), u8[5]);
        u8[6] = fmaf(w, bflo(hv.w), u8[6]);
        u8[7] = fmaf(w, bfhi(hv.w), u8[7]);
    }
    // sum the 8 sg-subgroups within each wave (lane bits 3..5)
#pragma unroll
    for (int o = 8; o <= 32; o <<= 1) {
#pragma unroll
        for (int mm = 0; mm < 8; ++mm) u8[mm] += __shfl_xor(u8[mm], o);
    }
    if (lane < 8) {
#pragma unroll
        for (int mm = 0; mm < 8; ++mm) red[wv * DSL + lane * 8 + mm] = u8[mm];
    }
    __syncthreads();
    if (t < DSL) {
        float acc = 0.f;
#pragma unroll
        for (int w2i = 0; w2i < W2C; ++w2i) acc += red[w2i * DSL + t];
        ubar[t] = acc;
    }
    __syncthreads();

    // --- Phase D: ctx = u @ W2 + b2 (16 waves, 4 j's each) ---
    {
        float acc = (wv == 0) ? b2[lane] : 0.f;
        for (int jj = wv * 4; jj < wv * 4 + 4; ++jj)
            acc = fmaf(ubar[jj], W2[jj * DSL + lane], acc);
        red[wv * DSL + lane] = acc;
    }
    __syncthreads();
    if (t < DSL) {
        float acc = 0.f;
#pragma unroll
        for (int w2i = 0; w2i < W2C; ++w2i) acc += red[w2i * DSL + t];
        ctx_out[(size_t)b * DSL + t] = acc;
    }

    // --- Phase E: top-K (descending value, ties -> lower index) ---
    for (int k = 0; k < KSEL; ++k) {
        // seed with s=t so an all -inf row still yields valid indices
        float bvv = scm[t];
        int bi = t;
#pragma unroll
        for (int kk = 1; kk < SS / T2; ++kk) {  // ascending index
            int s = t + kk * T2;
            float v = scm[s];
            if (v > bvv) { bvv = v; bi = s; }
        }
#pragma unroll
        for (int o = 1; o < 64; o <<= 1) {
            float ov = __shfl_xor(bvv, o);
            int oi = __shfl_xor(bi, o);
            if (ov > bvv || (ov == bvv && oi < bi)) { bvv = ov; bi = oi; }
        }
        if (lane == 0) { wargv[wv] = bvv; wargi[wv] = bi; }
        __syncthreads();
        if (t == 0) {
            float Bv = wargv[0]; int Bi = wargi[0];
            for (int w2i = 1; w2i < W2C; ++w2i) {
                float ov = wargv[w2i]; int oi = wargi[w2i];
                if (ov > Bv || (ov == Bv && oi < Bi)) { Bv = ov; Bi = oi; }
            }
            topidx[k] = Bi;
            scm[Bi] = -INFINITY;
        }
        __syncthreads();
    }

    // --- Phase F: sel = full f32 MLP recompute of the K selected rows ---
    if (t < KSEL * DIN) {
        int k = t >> 5, i = t & 31;
        xsel[k][i] = feats[((size_t)b * SS + topidx[k]) * DIN + i];
    }
    __syncthreads();
    if (wv < KSEL) {
        const int k = wv;
        float h = b1[lane];
#pragma unroll
        for (int i = 0; i < DIN; ++i) h = fmaf(xsel[k][i], W1[i * DSL + lane], h);
        h1sel[k][lane] = fmaxf(h, 0.f);
    }
    __syncthreads();
    if (wv < KSEL) {
        const int k = wv;
        float acc = b2[lane];
        for (int jj = 0; jj < DSL; ++jj)
            acc = fmaf(h1sel[k][jj], W2[jj * DSL + lane], acc);
        sel_out[((size_t)b * KSEL + k) * DSL + lane] = acc;
    }
}

extern "C" void kernel_launch(void* const* d_in, const int* in_sizes, int n_in,
                              void* d_out, int out_size, void* d_ws, size_t ws_size,
                              hipStream_t stream) {
    const float* feats = (const float*)d_in[0];
    const void*  mask  = d_in[1];
    const float* W1 = (const float*)d_in[2];
    const float* b1 = (const float*)d_in[3];
    const float* W2 = (const float*)d_in[4];
    const float* b2 = (const float*)d_in[5];
    const float* q  = (const float*)d_in[6];

    float* scores_ws = (float*)d_ws;
    unsigned short* h1_ws =
        (unsigned short*)((char*)d_ws + (size_t)BB * SS * sizeof(float));

    float* sel_out  = (float*)d_out;                       // B*K*64
    float* ctx_out  = sel_out + (size_t)BB * KSEL * DSL;   // B*64
    float* attn_out = ctx_out + (size_t)BB * DSL;          // B*S

    hipLaunchKernelGGL(k1_mlp_scores, dim3(BB * SS / 256), dim3(256), 0, stream,
                       feats, W1, b1, W2, b2, q, scores_ws, h1_ws);
    hipLaunchKernelGGL(k2_attend, dim3(BB), dim3(T2), 0, stream,
                       feats, mask, W1, b1, W2, b2, scores_ws, h1_ws,
                       sel_out, ctx_out, attn_out);
}